// Round 4
// baseline (89.285 us; speedup 1.0000x reference)
//
#include <hip/hip_runtime.h>

#define IN_CH 16
#define OUT_CH 32
#define NUM_INPUTS 144   // IN_CH * 3 * 3
#define H_ 32
#define W_ 32
#define TILE_H 8
#define LDS_H 10         // TILE_H + 2 halo
#define LDS_W 34         // W + 2 halo; 34 mod 32 == 2 -> 2 lanes/bank (free)
#define CSPLIT 8         // input channels per split-K block
#define TAPS (CSPLIT*9)  // 72

typedef __attribute__((ext_vector_type(2))) float f32x2;

// ---------------------------------------------------------------------------
// Prep: per (i,o) pair, params of y(p) = m0*p + b0 + (m1-m0)*max(p-p1, 0)
// (continuous at p1 -> reproduces both clipped extrapolation tails exactly).
// SoA float2 channel-pair layout: tabX[i*16 + pair], halves = ch 2p, 2p+1.
// Flat half index (i*16+(o>>1))*2+(o&1) == i*32+o == e, so scalar writes.
// ---------------------------------------------------------------------------
__global__ void apc_prep(const float* __restrict__ pos,
                         const float* __restrict__ val,
                         float* __restrict__ tabP, float* __restrict__ tabM,
                         float* __restrict__ tabD, float* __restrict__ tabB) {
    int e = blockIdx.x * 256 + threadIdx.x;   // 0..4607 = i*32 + o
    const float* pp = pos + e * 3;
    const float* vv = val + e * 3;
    float p0 = pp[0], p1 = pp[1], p2 = pp[2];
    float v0 = vv[0], v1 = vv[1], v2 = vv[2];
    float m0 = (v1 - v0) / (p1 - p0);
    float m1 = (v2 - v1) / (p2 - p1);
    tabP[e] = p1;
    tabM[e] = m0;
    tabD[e] = m1 - m0;
    tabB[e] = v0 - m0 * p0;
}

// ---------------------------------------------------------------------------
// Main: grid (32 spatial, 8 ch-quads, 2 c-splits), block 128 (2 waves).
// Thread = (thread-row j = tid>>5, col = tid&31); each thread computes TWO
// adjacent output rows (2j, 2j+1) x 4 output channels x 8 input channels.
// Row-pair sharing: per (c,kw) load 4 LDS row values instead of 6 -> LDS
// pipe (the bottleneck) drops 1.5x; table SGPRs are reused for both rows.
// Stride 34 == 2 (mod 32) -> exactly 2 lanes/bank on every LDS access (free).
// Split-K combine: atomicAdd into memset-zeroed out.
// ---------------------------------------------------------------------------
__global__ __launch_bounds__(128, 1) void apc_main(
        const float* __restrict__ x,
        const f32x2* __restrict__ tabP, const f32x2* __restrict__ tabM,
        const f32x2* __restrict__ tabD, const f32x2* __restrict__ tabB,
        float* __restrict__ out) {
    __shared__ float lx[CSPLIT * LDS_H * LDS_W];   // 10.9 KB
    __shared__ f32x2 b0s[2];

    int bx  = blockIdx.x;            // 0..31: b*4 + row_tile
    int b   = bx >> 2;
    int ho0 = (bx & 3) * TILE_H;
    int pr0 = blockIdx.y * 2;        // channel-pair base; o0 = pr0*2
    int c0  = blockIdx.z * CSPLIT;   // input-channel split
    int tid = threadIdx.x;
    int i0  = c0 * 9;                // first tap index of this split

    // Stage x tile with zero-padded halo (2720 floats, 128 threads).
    for (int idx = tid; idx < CSPLIT * LDS_H * LDS_W; idx += 128) {
        int c   = idx / (LDS_H * LDS_W);
        int rem = idx - c * (LDS_H * LDS_W);
        int r   = rem / LDS_W;
        int col = rem - r * LDS_W;
        int gr  = ho0 + r - 1;
        int gc  = col - 1;
        float v = 0.f;
        if ((unsigned)gr < (unsigned)H_ && (unsigned)gc < (unsigned)W_)
            v = x[((b * IN_CH + c0 + c) * H_ + gr) * W_ + gc];
        lx[idx] = v;
    }

    // Wave w reduces this split's b0 sum for channel-pair pr0+w.
    int wave = tid >> 6, lane = tid & 63;
    {
        f32x2 s = {0.f, 0.f};
        for (int t = lane; t < TAPS; t += 64)
            s += tabB[(i0 + t) * 16 + pr0 + wave];
        #pragma unroll
        for (int off = 32; off; off >>= 1) {
            s.x += __shfl_down(s.x, off);
            s.y += __shfl_down(s.y, off);
        }
        if (lane == 0) b0s[wave] = s;
    }
    __syncthreads();

    int j    = tid >> 5;             // 0..3 thread-row -> output rows 2j,2j+1
    int col  = tid & 31;
    int base = (2 * j) * LDS_W + col;

    f32x2 aA0 = {0,0}, hA0 = {0,0}, aA1 = {0,0}, hA1 = {0,0};  // row 2j
    f32x2 aB0 = {0,0}, hB0 = {0,0}, aB1 = {0,0}, hB1 = {0,0};  // row 2j+1
    const f32x2 zz = {0.f, 0.f};

    #pragma unroll
    for (int c = 0; c < CSPLIT; ++c) {
        #pragma unroll
        for (int kw = 0; kw < 3; ++kw) {
            // 4 shared input rows cover both output rows' 3x1 kh windows.
            float p0 = lx[c * (LDS_H * LDS_W) + base + 0 * LDS_W + kw];
            float p1 = lx[c * (LDS_H * LDS_W) + base + 1 * LDS_W + kw];
            float p2 = lx[c * (LDS_H * LDS_W) + base + 2 * LDS_W + kw];
            float p3 = lx[c * (LDS_H * LDS_W) + base + 3 * LDS_W + kw];
            float pa[4] = {p0, p1, p2, p3};
            #pragma unroll
            for (int kh = 0; kh < 3; ++kh) {
                int ti = (i0 + (c * 3 + kh) * 3 + kw) * 16;
                f32x2 P0 = tabP[ti + pr0], P1 = tabP[ti + pr0 + 1];
                f32x2 M0 = tabM[ti + pr0], M1 = tabM[ti + pr0 + 1];
                f32x2 D0 = tabD[ti + pr0], D1 = tabD[ti + pr0 + 1];
                f32x2 qA = {pa[kh],     pa[kh]};       // row 2j   uses rows 2j+kh
                f32x2 qB = {pa[kh + 1], pa[kh + 1]};   // row 2j+1 uses rows 2j+1+kh
                aA0 = __builtin_elementwise_fma(M0, qA, aA0);
                hA0 = __builtin_elementwise_fma(D0, __builtin_elementwise_max(qA - P0, zz), hA0);
                aA1 = __builtin_elementwise_fma(M1, qA, aA1);
                hA1 = __builtin_elementwise_fma(D1, __builtin_elementwise_max(qA - P1, zz), hA1);
                aB0 = __builtin_elementwise_fma(M0, qB, aB0);
                hB0 = __builtin_elementwise_fma(D0, __builtin_elementwise_max(qB - P0, zz), hB0);
                aB1 = __builtin_elementwise_fma(M1, qB, aB1);
                hB1 = __builtin_elementwise_fma(D1, __builtin_elementwise_max(qB - P1, zz), hB1);
            }
        }
    }

    aA0 += hA0 + b0s[0];  aA1 += hA1 + b0s[1];
    aB0 += hB0 + b0s[0];  aB1 += hB1 + b0s[1];

    int hoA = ho0 + 2 * j;
    int o0  = pr0 * 2;
    int obA = ((b * OUT_CH + o0) * H_ + hoA) * W_ + col;
    int HW  = H_ * W_;
    atomicAdd(&out[obA         ], aA0.x);
    atomicAdd(&out[obA +     HW], aA0.y);
    atomicAdd(&out[obA + 2 * HW], aA1.x);
    atomicAdd(&out[obA + 3 * HW], aA1.y);
    int obB = obA + W_;
    atomicAdd(&out[obB         ], aB0.x);
    atomicAdd(&out[obB +     HW], aB0.y);
    atomicAdd(&out[obB + 2 * HW], aB1.x);
    atomicAdd(&out[obB + 3 * HW], aB1.y);
}

extern "C" void kernel_launch(void* const* d_in, const int* in_sizes, int n_in,
                              void* d_out, int out_size, void* d_ws, size_t ws_size,
                              hipStream_t stream) {
    const float* x   = (const float*)d_in[0];
    const float* pos = (const float*)d_in[1];
    const float* val = (const float*)d_in[2];

    // SoA tables in workspace: 4 arrays x 4608 floats = 18432 B each.
    char* w = (char*)d_ws;
    float* tabP = (float*)(w);
    float* tabM = (float*)(w + 18432);
    float* tabD = (float*)(w + 36864);
    float* tabB = (float*)(w + 55296);

    // d_out is poisoned 0xAA before every timed call; zero it for the
    // split-K atomic combine (async memset is graph-capturable).
    hipMemsetAsync(d_out, 0, (size_t)out_size * sizeof(float), stream);

    apc_prep<<<18, 256, 0, stream>>>(pos, val, tabP, tabM, tabD, tabB);

    dim3 grid(32, 8, 2);
    apc_main<<<grid, 128, 0, stream>>>(x, (const f32x2*)tabP, (const f32x2*)tabM,
                                       (const f32x2*)tabD, (const f32x2*)tabB,
                                       (float*)d_out);
}

// Round 5
// 69.638 us; speedup vs baseline: 1.2821x; 1.2821x over previous
//
#include <hip/hip_runtime.h>

#define IN_CH 16
#define OUT_CH 32
#define NUM_INPUTS 144   // IN_CH * 3 * 3
#define H_ 32
#define W_ 32
#define TILE_H 8
#define LDS_H 10         // TILE_H + 2 halo
#define LDS_W 34         // W + 2 halo; 34 mod 32 == 2 -> 2 lanes/bank (free)
#define CSPLIT 8         // input channels per split-K block
#define TAPS (CSPLIT*9)  // 72
#define CHW (LDS_H * LDS_W)

typedef __attribute__((ext_vector_type(2))) float f32x2;

// ---------------------------------------------------------------------------
// Prep: per (i,o) pair, params of y(p) = m0*p + b0 + (m1-m0)*max(p-p1, 0)
// (continuous at p1 -> reproduces both clipped extrapolation tails exactly).
//
// tabT layout is per-block-contiguous so main can stage its whole table
// slice with ONE coalesced float4 burst:
//   tabT[(o>>2)*NUM_INPUTS*12 + i*12 + {0..3:P, 4..7:M, 8..11:D} + (o&3)]
// i.e. per (channel-quad g, tap i): 48 B = [P x4ch][M x4ch][D x4ch].
// tabB[e], e = i*32+o, feeds the b0-sum reduction (vector loads in main).
// ---------------------------------------------------------------------------
__global__ void apc_prep(const float* __restrict__ pos,
                         const float* __restrict__ val,
                         float* __restrict__ tabT,
                         float* __restrict__ tabB) {
    int e = blockIdx.x * 256 + threadIdx.x;   // 0..4607 = i*32 + o
    const float* pp = pos + e * 3;
    const float* vv = val + e * 3;
    float p0 = pp[0], p1 = pp[1], p2 = pp[2];
    float v0 = vv[0], v1 = vv[1], v2 = vv[2];
    float m0 = (v1 - v0) / (p1 - p0);
    float m1 = (v2 - v1) / (p2 - p1);
    int i = e >> 5, o = e & 31;
    float* dst = tabT + (o >> 2) * (NUM_INPUTS * 12) + i * 12 + (o & 3);
    dst[0] = p1;
    dst[4] = m0;
    dst[8] = m1 - m0;
    tabB[e] = v0 - m0 * p0;
}

// ---------------------------------------------------------------------------
// Main: grid (32 spatial, 8 ch-quads, 2 c-splits), block 256 = 4 waves.
// NOTHING in the hot loop touches global memory: both the x tile AND the
// table slice live in LDS (staged once per block with coalesced vector
// loads, latency overlapped across 8 waves/CU).  This removes the per-tap
// scalar-load (s_load/lgkmcnt) serialization that made R1-R4 mains 33-45us
// latency-bound at 7% VALUBusy on cold L2.
// Hot-loop LDS traffic per wave: 72 patch ds_read_b32 (stride 34 == 2 mod
// 32 -> 2 lanes/bank, free) + 216 wave-uniform ds_read_b128 (same-address
// broadcast, conflict-free).
// Split-K combine: atomicAdd into memset-zeroed out.
// ---------------------------------------------------------------------------
__global__ __launch_bounds__(256, 2) void apc_main(
        const float* __restrict__ x,
        const float* __restrict__ tabT,
        const f32x2* __restrict__ tabB,
        float* __restrict__ out) {
    __shared__ float lx[CSPLIT * CHW];    // 2720 floats = 10.9 KB
    __shared__ float lt[TAPS * 12];       //  864 floats =  3.5 KB
    __shared__ f32x2 b0s[2];

    int bx  = blockIdx.x;            // 0..31: b*4 + row_tile
    int b   = bx >> 2;
    int ho0 = (bx & 3) * TILE_H;
    int g   = blockIdx.y;            // channel-quad: o = 4g..4g+3
    int c0  = blockIdx.z * CSPLIT;   // input-channel split
    int tid = threadIdx.x;
    int i0  = c0 * 9;                // first tap index of this split

    // Stage x tile with zero-padded halo (2720 floats).
    for (int idx = tid; idx < CSPLIT * CHW; idx += 256) {
        int c   = idx / CHW;
        int rem = idx - c * CHW;
        int r   = rem / LDS_W;
        int col = rem - r * LDS_W;
        int gr  = ho0 + r - 1;
        int gc  = col - 1;
        float v = 0.f;
        if ((unsigned)gr < (unsigned)H_ && (unsigned)gc < (unsigned)W_)
            v = x[((b * IN_CH + c0 + c) * H_ + gr) * W_ + gc];
        lx[idx] = v;
    }

    // Stage this block's table slice: 864 floats, contiguous -> 216 float4.
    {
        const float4* src = (const float4*)(tabT + (g * NUM_INPUTS + i0) * 12);
        if (tid < TAPS * 3) ((float4*)lt)[tid] = src[tid];
    }

    // Wave w reduces this split's b0 sum for channel-pair 2g+w (vector loads).
    int wave = tid >> 6, lane = tid & 63;
    if (wave < 2) {
        int pr = 2 * g + wave;
        f32x2 s = {0.f, 0.f};
        for (int t = lane; t < TAPS; t += 64)
            s += tabB[(i0 + t) * 16 + pr];
        #pragma unroll
        for (int off = 32; off; off >>= 1) {
            s.x += __shfl_down(s.x, off);
            s.y += __shfl_down(s.y, off);
        }
        if (lane == 0) b0s[wave] = s;
    }
    __syncthreads();

    int rl   = tid >> 5;             // 0..7 local output row
    int col  = tid & 31;
    int base = rl * LDS_W + col;

    f32x2 a0 = {0,0}, h0 = {0,0};    // channels 4g, 4g+1
    f32x2 a1 = {0,0}, h1 = {0,0};    // channels 4g+2, 4g+3
    const f32x2 zz = {0.f, 0.f};

    #pragma unroll
    for (int c = 0; c < CSPLIT; ++c) {
        #pragma unroll
        for (int kh = 0; kh < 3; ++kh) {
            #pragma unroll
            for (int kw = 0; kw < 3; ++kw) {
                int t = (c * 3 + kh) * 3 + kw;
                float p = lx[c * CHW + kh * LDS_W + kw + base];
                const float* tp = &lt[t * 12];         // 16B-aligned (48B/tap)
                float4 qP = *(const float4*)(tp);      // P: ch 4g..4g+3
                float4 qM = *(const float4*)(tp + 4);  // M
                float4 qD = *(const float4*)(tp + 8);  // D
                f32x2 pb = {p, p};
                f32x2 P0 = {qP.x, qP.y}, P1 = {qP.z, qP.w};
                f32x2 M0 = {qM.x, qM.y}, M1 = {qM.z, qM.w};
                f32x2 D0 = {qD.x, qD.y}, D1 = {qD.z, qD.w};
                a0 = __builtin_elementwise_fma(M0, pb, a0);
                h0 = __builtin_elementwise_fma(D0, __builtin_elementwise_max(pb - P0, zz), h0);
                a1 = __builtin_elementwise_fma(M1, pb, a1);
                h1 = __builtin_elementwise_fma(D1, __builtin_elementwise_max(pb - P1, zz), h1);
            }
        }
    }

    a0 += h0 + b0s[0];
    a1 += h1 + b0s[1];

    int ho = ho0 + rl;
    int o0 = 4 * g;
    int ob = ((b * OUT_CH + o0) * H_ + ho) * W_ + col;
    int HW = H_ * W_;
    atomicAdd(&out[ob         ], a0.x);
    atomicAdd(&out[ob +     HW], a0.y);
    atomicAdd(&out[ob + 2 * HW], a1.x);
    atomicAdd(&out[ob + 3 * HW], a1.y);
}

extern "C" void kernel_launch(void* const* d_in, const int* in_sizes, int n_in,
                              void* d_out, int out_size, void* d_ws, size_t ws_size,
                              hipStream_t stream) {
    const float* x   = (const float*)d_in[0];
    const float* pos = (const float*)d_in[1];
    const float* val = (const float*)d_in[2];

    // Workspace: tabT 8*144*12*4 = 55296 B, then tabB 4608*4 = 18432 B.
    char* w = (char*)d_ws;
    float* tabT = (float*)(w);
    float* tabB = (float*)(w + 55296);

    // d_out is poisoned 0xAA before every timed call; zero it for the
    // split-K atomic combine (async memset is graph-capturable).
    hipMemsetAsync(d_out, 0, (size_t)out_size * sizeof(float), stream);

    apc_prep<<<18, 256, 0, stream>>>(pos, val, tabT, tabB);

    dim3 grid(32, 8, 2);
    apc_main<<<grid, 256, 0, stream>>>(x, tabT, (const f32x2*)tabB,
                                       (float*)d_out);
}